// Round 11
// baseline (179.331 us; speedup 1.0000x reference)
//
#include <hip/hip_runtime.h>
#include <hip/hip_bf16.h>
#include <math.h>

// ---------------------------------------------------------------------------
// GCN 3-layer forward: gcn_norm (self-loops, sym D^-1/2) + 3x (GEMM -> CSR
// aggregate) with fused bias/ReLU and final log-softmax.
// R11: fused agg_i+gemm_{i+1}. The agg phase parks the node's activation row
// (post bias+ReLU) in LDS (8 nodes x 64 f32/block); a gemm phase in the same
// block computes Hs_next = bf16(dinv*(x@W)) directly. Kills the bufF f32
// round-trip (2 x 25.6 MB) and 2 dispatches. 7 dispatches total.
// ---------------------------------------------------------------------------

#define BSHIFT 10           // bucket = col >> 10 (1024 nodes/bucket)
#define CHUNK 2048          // edges per bucketA workgroup
#define CAP 24576           // per-bucket edge capacity (mean 16384, +64 sigma)

__global__ __launch_bounds__(64) void tinyzero_kernel(int* __restrict__ p) {
  p[threadIdx.x] = 0;
}

// ---- phase 1: bucket edges by col>>BSHIFT into fixed-capacity regions ------

__global__ __launch_bounds__(256) void bucketA_kernel(const int* __restrict__ row,
                                                      const int* __restrict__ col,
                                                      int* __restrict__ bcursor,
                                                      int2* __restrict__ tmp, int e) {
  __shared__ int bcnt[64], bstart[64], bbase[64];
  __shared__ int2 stage[CHUNK];
  int tid = threadIdx.x;
  int base = blockIdx.x * CHUNK;
  int cnt = e - base;
  if (cnt > CHUNK) cnt = CHUNK;
  if (tid < 64) bcnt[tid] = 0;
  __syncthreads();

  int2 ed[CHUNK / 256];
  int rk[CHUNK / 256];
#pragma unroll
  for (int k = 0; k < CHUNK / 256; ++k) {
    int j = tid + k * 256;
    if (j < cnt) {
      int c = col[base + j], r = row[base + j];
      ed[k] = make_int2(c, r);
      rk[k] = atomicAdd(&bcnt[c >> BSHIFT], 1);
    }
  }
  __syncthreads();
  if (tid < 64) {  // wave 0: exclusive scan of bcnt + reserve bucket ranges
    int v = bcnt[tid];
    int run = v;
#pragma unroll
    for (int off = 1; off < 64; off <<= 1) {
      int t = __shfl_up(run, off);
      if (tid >= off) run += t;
    }
    bstart[tid] = run - v;
    if (v > 0) bbase[tid] = atomicAdd(&bcursor[tid], v);
  }
  __syncthreads();
#pragma unroll
  for (int k = 0; k < CHUNK / 256; ++k) {
    int j = tid + k * 256;
    if (j < cnt) stage[bstart[ed[k].x >> BSHIFT] + rk[k]] = ed[k];
  }
  __syncthreads();
  for (int s = tid; s < cnt; s += 256) {  // coalesced bucket-grouped write-out
    int2 ev = stage[s];
    int b = ev.x >> BSHIFT;
    tmp[(size_t)b * CAP + bbase[b] + (s - bstart[b])] = ev;
  }
}

// ---- phase 2: per-bucket LDS histogram + scan + scatter --------------------
// Emits meta[node] = {csr_offset, deg, dinv_bits, 0}, dinv[node], csr rows.

__global__ __launch_bounds__(256) void scatterB_kernel(const int2* __restrict__ tmp,
                                                       const int* __restrict__ bcursor,
                                                       int4* __restrict__ meta,
                                                       float* __restrict__ dinv,
                                                       int* __restrict__ csr, int n) {
  __shared__ int cnt[1 << BSHIFT];
  __shared__ int part[256];
  int tid = threadIdx.x;
  int b = blockIdx.x;
  int node0 = b << BSHIFT;
  int m = bcursor[b];  // edges in this bucket
  const int2* src = tmp + (size_t)b * CAP;

  for (int t = tid; t < (1 << BSHIFT); t += 256) cnt[t] = 0;
  __syncthreads();
  for (int i = tid; i < m; i += 256)
    atomicAdd(&cnt[src[i].x & ((1 << BSHIFT) - 1)], 1);
  __syncthreads();

  int c0 = cnt[tid * 4 + 0], c1 = cnt[tid * 4 + 1];
  int c2 = cnt[tid * 4 + 2], c3 = cnt[tid * 4 + 3];
  int lsum = c0 + c1 + c2 + c3;
  part[tid] = lsum;
  __syncthreads();
#pragma unroll
  for (int off = 1; off < 256; off <<= 1) {
    int t = (tid >= off) ? part[tid - off] : 0;
    __syncthreads();
    part[tid] += t;
    __syncthreads();
  }
  int e0 = (tid == 0 ? 0 : part[tid - 1]);
  int e1 = e0 + c0, e2 = e1 + c1, e3 = e2 + c2;
  int base = b * CAP;  // csr is bucket-major with the same CAP

  int nd = node0 + tid * 4;
  if (nd + 0 < n) { float d = rsqrtf((float)(c0 + 1)); meta[nd + 0] = make_int4(base + e0, c0, __float_as_int(d), 0); dinv[nd + 0] = d; }
  if (nd + 1 < n) { float d = rsqrtf((float)(c1 + 1)); meta[nd + 1] = make_int4(base + e1, c1, __float_as_int(d), 0); dinv[nd + 1] = d; }
  if (nd + 2 < n) { float d = rsqrtf((float)(c2 + 1)); meta[nd + 2] = make_int4(base + e2, c2, __float_as_int(d), 0); dinv[nd + 2] = d; }
  if (nd + 3 < n) { float d = rsqrtf((float)(c3 + 1)); meta[nd + 3] = make_int4(base + e3, c3, __float_as_int(d), 0); dinv[nd + 3] = d; }
  __syncthreads();
  cnt[tid * 4 + 0] = e0; cnt[tid * 4 + 1] = e1;
  cnt[tid * 4 + 2] = e2; cnt[tid * 4 + 3] = e3;
  __syncthreads();

  for (int i = tid; i < m; i += 256) {
    int2 ev = src[i];
    int pos = atomicAdd(&cnt[ev.x & ((1 << BSHIFT) - 1)], 1);
    csr[base + pos] = ev.y;
  }
}

// ---- dense GEMM: Hs[n][F] = bf16(dinv[n] * (X[n][K] @ W[K][F])) ------------

template <int K, int F>
__global__ __launch_bounds__(256) void gemm_kernel(const float* __restrict__ X,
                                                   const float* __restrict__ W,
                                                   const float* __restrict__ dinv,
                                                   __hip_bfloat16* __restrict__ Y, int n) {
  __shared__ float xs[16][K];
  int tid = threadIdx.x;
  int node0 = blockIdx.x * 16;
  constexpr int KV = K / 4;
  const float4* X4 = (const float4*)X;
  for (int i = tid; i < 16 * KV; i += 256) {
    int r = i / KV, c = i % KV;
    int nd = node0 + r;
    float4 v = make_float4(0.f, 0.f, 0.f, 0.f);
    if (nd < n) v = X4[(size_t)nd * KV + c];
    ((float4*)&xs[r][0])[c] = v;
  }
  __syncthreads();
  int g = tid >> 6, lane = tid & 63;
  if (lane < F) {
    float acc0 = 0.f, acc1 = 0.f, acc2 = 0.f, acc3 = 0.f;
#pragma unroll 8
    for (int k = 0; k < K; ++k) {
      float w = W[k * F + lane];
      acc0 += xs[g * 4 + 0][k] * w;
      acc1 += xs[g * 4 + 1][k] * w;
      acc2 += xs[g * 4 + 2][k] * w;
      acc3 += xs[g * 4 + 3][k] * w;
    }
    float accs[4] = {acc0, acc1, acc2, acc3};
#pragma unroll
    for (int j = 0; j < 4; ++j) {
      int nd = node0 + g * 4 + j;
      if (nd < n) Y[(size_t)nd * F + lane] = __float2bfloat16(accs[j] * dinv[nd]);
    }
  }
}

// ---- bf16 helpers ----------------------------------------------------------

__device__ __forceinline__ float bflo(unsigned int u) {
  return __uint_as_float(u << 16);
}
__device__ __forceinline__ float bfhi(unsigned int u) {
  return __uint_as_float(u & 0xffff0000u);
}

// ---- fused agg(layer i) + gemm(layer i+1) ----------------------------------
// Agg phase (R10 mapping: half-wave per node, 2 edge slots, 16 lanes x uint2):
// x = relu(dinv_c*(Hs[self] + sum Hs[nbr]) + bias) -> LDS [8][64].
// Gemm phase: Hs_out[node][fo] = bf16(dinv_c * sum_k x[k]*W[k][fo]).

template <int FOUT>
__global__ __launch_bounds__(256) void fused_agg_gemm_kernel(
    const unsigned short* __restrict__ Hs, const int* __restrict__ csr,
    const int4* __restrict__ meta, const float* __restrict__ bias,
    const float* __restrict__ W, __hip_bfloat16* __restrict__ Yout, int n) {
  constexpr int F = 64;
  __shared__ float lds_x[8][F];
  __shared__ float lds_di[8];
  int tid = threadIdx.x;
  int wv = (blockIdx.x * 256 + tid) >> 6;
  int lane = tid & 63;
  int half = lane >> 5;
  int l32 = lane & 31;
  int sub = l32 >> 4;
  int fid = lane & 15;
  int node = wv * 2 + half;
  int nl = (tid >> 6) * 2 + half;            // node slot in LDS (0..7)
  bool valid = node < n;

  int s = 0, e = 0;
  float di = 0.f;
  if (valid) {
    int4 mt = meta[node];                    // {off, deg, dinv_bits, 0}
    s = mt.x; e = mt.x + mt.y;
    di = __int_as_float(mt.z);
  }

  float a0 = 0.f, a1 = 0.f, a2 = 0.f, a3 = 0.f;
  if (valid && sub == 0) {                   // self-loop counted once
    uint2 u = *(const uint2*)(Hs + (size_t)node * F + 4 * fid);
    a0 = bflo(u.x); a1 = bfhi(u.x); a2 = bflo(u.y); a3 = bfhi(u.y);
  }

  int hbase = 32 * half;
  for (int base = s; base < e; base += 32) {
    int rem = e - base;
    int cnt = rem < 32 ? rem : 32;
    int p = csr[base + (l32 < cnt ? l32 : 0)];
    int j = 0;
    for (; j + 8 <= cnt; j += 8) {
      int r0 = __shfl(p, j + 0 + sub + hbase);
      int r1 = __shfl(p, j + 2 + sub + hbase);
      int r2 = __shfl(p, j + 4 + sub + hbase);
      int r3 = __shfl(p, j + 6 + sub + hbase);
      uint2 u0 = *(const uint2*)(Hs + (size_t)r0 * F + 4 * fid);
      uint2 u1 = *(const uint2*)(Hs + (size_t)r1 * F + 4 * fid);
      uint2 u2 = *(const uint2*)(Hs + (size_t)r2 * F + 4 * fid);
      uint2 u3 = *(const uint2*)(Hs + (size_t)r3 * F + 4 * fid);
      a0 += bflo(u0.x); a1 += bfhi(u0.x); a2 += bflo(u0.y); a3 += bfhi(u0.y);
      a0 += bflo(u1.x); a1 += bfhi(u1.x); a2 += bflo(u1.y); a3 += bfhi(u1.y);
      a0 += bflo(u2.x); a1 += bfhi(u2.x); a2 += bflo(u2.y); a3 += bfhi(u2.y);
      a0 += bflo(u3.x); a1 += bfhi(u3.x); a2 += bflo(u3.y); a3 += bfhi(u3.y);
    }
    for (; j < cnt; j += 2) {
      int idx = j + sub;
      int r = __shfl(p, (idx < cnt ? idx : j) + hbase);
      if (idx < cnt) {
        uint2 u = *(const uint2*)(Hs + (size_t)r * F + 4 * fid);
        a0 += bflo(u.x); a1 += bfhi(u.x); a2 += bflo(u.y); a3 += bfhi(u.y);
      }
    }
  }

  a0 += __shfl_xor(a0, 16);
  a1 += __shfl_xor(a1, 16);
  a2 += __shfl_xor(a2, 16);
  a3 += __shfl_xor(a3, 16);

  if (valid && sub == 0) {
    float4 bv = *(const float4*)(bias + 4 * fid);
    float v0 = a0 * di + bv.x, v1 = a1 * di + bv.y;
    float v2 = a2 * di + bv.z, v3 = a3 * di + bv.w;
    v0 = v0 > 0.f ? v0 : 0.f;
    v1 = v1 > 0.f ? v1 : 0.f;
    v2 = v2 > 0.f ? v2 : 0.f;
    v3 = v3 > 0.f ? v3 : 0.f;
    ((float4*)&lds_x[nl][0])[fid] = make_float4(v0, v1, v2, v3);
    if (fid == 0) lds_di[nl] = di;
  }
  __syncthreads();

  // gemm phase: 32 threads per node, 1-2 outputs each, K = 64
  int gn = tid >> 5;                         // node slot 0..7
  int gnode = blockIdx.x * 8 + gn;
  if (gnode < n) {
    float gdi = lds_di[gn];
    const float* xr = &lds_x[gn][0];
    for (int fo = tid & 31; fo < FOUT; fo += 32) {
      float acc = 0.f;
#pragma unroll 8
      for (int k = 0; k < F; ++k) acc += xr[k] * W[k * FOUT + fo];
      Yout[(size_t)gnode * FOUT + fo] = __float2bfloat16(acc * gdi);
    }
  }
}

// ---- final aggregate: half-wave per node + bias + log_softmax (F=40) -------

template <int F>
__global__ __launch_bounds__(256) void agg_final_kernel(
    const unsigned short* __restrict__ Hs, const int* __restrict__ csr,
    const int4* __restrict__ meta, const float* __restrict__ bias,
    float* __restrict__ Y, int n) {
  constexpr int FQ = F / 4;                  // 10 feature quads for F=40
  int wv = (blockIdx.x * 256 + threadIdx.x) >> 6;
  int lane = threadIdx.x & 63;
  int half = lane >> 5;
  int l32 = lane & 31;
  int sub = l32 >> 4;
  int fid = lane & 15;
  int node = wv * 2 + half;
  if (node >= n) return;
  bool activeF = fid < FQ;
  int hbase = 32 * half;

  int4 mt = meta[node];
  int s = mt.x, e = mt.x + mt.y;
  float di = __int_as_float(mt.z);

  float a0 = 0.f, a1 = 0.f, a2 = 0.f, a3 = 0.f;
  if (sub == 0 && activeF) {
    uint2 u = *(const uint2*)(Hs + (size_t)node * F + 4 * fid);
    a0 = bflo(u.x); a1 = bfhi(u.x); a2 = bflo(u.y); a3 = bfhi(u.y);
  }

  for (int base = s; base < e; base += 32) {
    int rem = e - base;
    int cnt = rem < 32 ? rem : 32;
    int p = csr[base + (l32 < cnt ? l32 : 0)];
    int j = 0;
    for (; j + 8 <= cnt; j += 8) {
      int r0 = __shfl(p, j + 0 + sub + hbase);
      int r1 = __shfl(p, j + 2 + sub + hbase);
      int r2 = __shfl(p, j + 4 + sub + hbase);
      int r3 = __shfl(p, j + 6 + sub + hbase);
      if (activeF) {
        uint2 u0 = *(const uint2*)(Hs + (size_t)r0 * F + 4 * fid);
        uint2 u1 = *(const uint2*)(Hs + (size_t)r1 * F + 4 * fid);
        uint2 u2 = *(const uint2*)(Hs + (size_t)r2 * F + 4 * fid);
        uint2 u3 = *(const uint2*)(Hs + (size_t)r3 * F + 4 * fid);
        a0 += bflo(u0.x); a1 += bfhi(u0.x); a2 += bflo(u0.y); a3 += bfhi(u0.y);
        a0 += bflo(u1.x); a1 += bfhi(u1.x); a2 += bflo(u1.y); a3 += bfhi(u1.y);
        a0 += bflo(u2.x); a1 += bfhi(u2.x); a2 += bflo(u2.y); a3 += bfhi(u2.y);
        a0 += bflo(u3.x); a1 += bfhi(u3.x); a2 += bflo(u3.y); a3 += bfhi(u3.y);
      }
    }
    for (; j < cnt; j += 2) {
      int idx = j + sub;
      int r = __shfl(p, (idx < cnt ? idx : j) + hbase);
      if (activeF && idx < cnt) {
        uint2 u = *(const uint2*)(Hs + (size_t)r * F + 4 * fid);
        a0 += bflo(u.x); a1 += bfhi(u.x); a2 += bflo(u.y); a3 += bfhi(u.y);
      }
    }
  }

  a0 += __shfl_xor(a0, 16);
  a1 += __shfl_xor(a1, 16);
  a2 += __shfl_xor(a2, 16);
  a3 += __shfl_xor(a3, 16);

  float v0 = -INFINITY, v1 = -INFINITY, v2 = -INFINITY, v3 = -INFINITY;
  if (activeF) {
    float4 bv = *(const float4*)(bias + 4 * fid);
    v0 = a0 * di + bv.x; v1 = a1 * di + bv.y;
    v2 = a2 * di + bv.z; v3 = a3 * di + bv.w;
  }
  float m = fmaxf(fmaxf(v0, v1), fmaxf(v2, v3));
#pragma unroll
  for (int off = 8; off; off >>= 1) m = fmaxf(m, __shfl_xor(m, off));
  float ex = 0.f;
  if (activeF)
    ex = expf(v0 - m) + expf(v1 - m) + expf(v2 - m) + expf(v3 - m);
#pragma unroll
  for (int off = 8; off; off >>= 1) ex += __shfl_xor(ex, off);
  float lg = m + logf(ex);
  if (sub == 0 && activeF) {
    *(float4*)(Y + (size_t)node * F + 4 * fid) =
        make_float4(v0 - lg, v1 - lg, v2 - lg, v3 - lg);
  }
}

// ---------------------------------------------------------------------------

extern "C" void kernel_launch(void* const* d_in, const int* in_sizes, int n_in,
                              void* d_out, int out_size, void* d_ws, size_t ws_size,
                              hipStream_t stream) {
  const float* x  = (const float*)d_in[0];
  const int*   ei = (const int*)d_in[1];
  const float* W1 = (const float*)d_in[2];
  const float* b1 = (const float*)d_in[3];
  const float* W2 = (const float*)d_in[4];
  const float* b2 = (const float*)d_in[5];
  const float* W3 = (const float*)d_in[6];
  const float* b3 = (const float*)d_in[7];
  float* out = (float*)d_out;

  const int N = in_sizes[0] / 128;
  const int E = in_sizes[1] / 2;
  const int* erow = ei;       // edge_index[0] = source
  const int* ecol = ei + E;   // edge_index[1] = target

  const int nbuckets = (N + (1 << BSHIFT) - 1) >> BSHIFT;  // 49 (<=64)

  auto align_up = [](size_t v) { return (v + 255) & ~(size_t)255; };
  char* ws = (char*)d_ws;
  size_t off = 0;
  int* bcursor  = (int*)(ws + off); off += align_up(64 * 4);
  int4* meta    = (int4*)(ws + off); off += align_up((size_t)N * 16);
  float* dinv   = (float*)(ws + off); off += align_up((size_t)N * 4);
  int* csr      = (int*)(ws + off); off += align_up((size_t)nbuckets * CAP * 4);
  int2* tmp     = (int2*)(ws + off); off += align_up((size_t)nbuckets * CAP * 8);
  __hip_bfloat16* bufA = (__hip_bfloat16*)(ws + off); off += align_up((size_t)N * 64 * 2);
  __hip_bfloat16* bufB = (__hip_bfloat16*)(ws + off); off += align_up((size_t)N * 64 * 2);
  (void)ws_size;

  const int cb = (E + CHUNK - 1) / CHUNK;

  tinyzero_kernel<<<1, 64, 0, stream>>>(bcursor);
  bucketA_kernel<<<cb, 256, 0, stream>>>(erow, ecol, bcursor, tmp, E);
  scatterB_kernel<<<nbuckets, 256, 0, stream>>>(tmp, bcursor, meta, dinv, csr, N);

  const int gemm_blocks = (N + 15) / 16;
  const int node8_blocks = (N + 7) / 8;   // 4 waves x 2 nodes per 256-thread block

  gemm_kernel<128, 64><<<gemm_blocks, 256, 0, stream>>>(x, W1, dinv, bufA, N);
  fused_agg_gemm_kernel<64><<<node8_blocks, 256, 0, stream>>>(
      (const unsigned short*)bufA, csr, meta, b1, W2, bufB, N);
  fused_agg_gemm_kernel<40><<<node8_blocks, 256, 0, stream>>>(
      (const unsigned short*)bufB, csr, meta, b2, W3, bufA, N);
  agg_final_kernel<40><<<node8_blocks, 256, 0, stream>>>(
      (const unsigned short*)bufA, csr, meta, b3, out, N);
}

// Round 12
// 165.435 us; speedup vs baseline: 1.0840x; 1.0840x over previous
//
#include <hip/hip_runtime.h>
#include <hip/hip_bf16.h>
#include <math.h>

// ---------------------------------------------------------------------------
// GCN 3-layer forward: gcn_norm (self-loops, sym D^-1/2) + 3x (GEMM -> CSR
// aggregate) with fused bias/ReLU and final log-softmax.
// R12: revert R11 fusion (in-block gemm was less efficient than standalone).
// Quarter-wave-per-node agg: lane = q*16 + sub*8 + fid; 8 lanes x uint4
// (8 bf16) = one 128B row; 4 nodes + 2 edge slots per wave -> one gather
// instruction fetches 8 rows (1024B, full wave load). 12.5k waves.
// ---------------------------------------------------------------------------

#define BSHIFT 10           // bucket = col >> 10 (1024 nodes/bucket)
#define CHUNK 2048          // edges per bucketA workgroup
#define CAP 24576           // per-bucket edge capacity (mean 16384, +64 sigma)

__global__ __launch_bounds__(64) void tinyzero_kernel(int* __restrict__ p) {
  p[threadIdx.x] = 0;
}

// ---- phase 1: bucket edges by col>>BSHIFT into fixed-capacity regions ------

__global__ __launch_bounds__(256) void bucketA_kernel(const int* __restrict__ row,
                                                      const int* __restrict__ col,
                                                      int* __restrict__ bcursor,
                                                      int2* __restrict__ tmp, int e) {
  __shared__ int bcnt[64], bstart[64], bbase[64];
  __shared__ int2 stage[CHUNK];
  int tid = threadIdx.x;
  int base = blockIdx.x * CHUNK;
  int cnt = e - base;
  if (cnt > CHUNK) cnt = CHUNK;
  if (tid < 64) bcnt[tid] = 0;
  __syncthreads();

  int2 ed[CHUNK / 256];
  int rk[CHUNK / 256];
#pragma unroll
  for (int k = 0; k < CHUNK / 256; ++k) {
    int j = tid + k * 256;
    if (j < cnt) {
      int c = col[base + j], r = row[base + j];
      ed[k] = make_int2(c, r);
      rk[k] = atomicAdd(&bcnt[c >> BSHIFT], 1);
    }
  }
  __syncthreads();
  if (tid < 64) {  // wave 0: exclusive scan of bcnt + reserve bucket ranges
    int v = bcnt[tid];
    int run = v;
#pragma unroll
    for (int off = 1; off < 64; off <<= 1) {
      int t = __shfl_up(run, off);
      if (tid >= off) run += t;
    }
    bstart[tid] = run - v;
    if (v > 0) bbase[tid] = atomicAdd(&bcursor[tid], v);
  }
  __syncthreads();
#pragma unroll
  for (int k = 0; k < CHUNK / 256; ++k) {
    int j = tid + k * 256;
    if (j < cnt) stage[bstart[ed[k].x >> BSHIFT] + rk[k]] = ed[k];
  }
  __syncthreads();
  for (int s = tid; s < cnt; s += 256) {  // coalesced bucket-grouped write-out
    int2 ev = stage[s];
    int b = ev.x >> BSHIFT;
    tmp[(size_t)b * CAP + bbase[b] + (s - bstart[b])] = ev;
  }
}

// ---- phase 2: per-bucket LDS histogram + scan + scatter --------------------
// Emits meta[node] = {csr_offset, deg, dinv_bits, 0}, dinv[node], csr rows.

__global__ __launch_bounds__(256) void scatterB_kernel(const int2* __restrict__ tmp,
                                                       const int* __restrict__ bcursor,
                                                       int4* __restrict__ meta,
                                                       float* __restrict__ dinv,
                                                       int* __restrict__ csr, int n) {
  __shared__ int cnt[1 << BSHIFT];
  __shared__ int part[256];
  int tid = threadIdx.x;
  int b = blockIdx.x;
  int node0 = b << BSHIFT;
  int m = bcursor[b];  // edges in this bucket
  const int2* src = tmp + (size_t)b * CAP;

  for (int t = tid; t < (1 << BSHIFT); t += 256) cnt[t] = 0;
  __syncthreads();
  for (int i = tid; i < m; i += 256)
    atomicAdd(&cnt[src[i].x & ((1 << BSHIFT) - 1)], 1);
  __syncthreads();

  int c0 = cnt[tid * 4 + 0], c1 = cnt[tid * 4 + 1];
  int c2 = cnt[tid * 4 + 2], c3 = cnt[tid * 4 + 3];
  int lsum = c0 + c1 + c2 + c3;
  part[tid] = lsum;
  __syncthreads();
#pragma unroll
  for (int off = 1; off < 256; off <<= 1) {
    int t = (tid >= off) ? part[tid - off] : 0;
    __syncthreads();
    part[tid] += t;
    __syncthreads();
  }
  int e0 = (tid == 0 ? 0 : part[tid - 1]);
  int e1 = e0 + c0, e2 = e1 + c1, e3 = e2 + c2;
  int base = b * CAP;  // csr is bucket-major with the same CAP

  int nd = node0 + tid * 4;
  if (nd + 0 < n) { float d = rsqrtf((float)(c0 + 1)); meta[nd + 0] = make_int4(base + e0, c0, __float_as_int(d), 0); dinv[nd + 0] = d; }
  if (nd + 1 < n) { float d = rsqrtf((float)(c1 + 1)); meta[nd + 1] = make_int4(base + e1, c1, __float_as_int(d), 0); dinv[nd + 1] = d; }
  if (nd + 2 < n) { float d = rsqrtf((float)(c2 + 1)); meta[nd + 2] = make_int4(base + e2, c2, __float_as_int(d), 0); dinv[nd + 2] = d; }
  if (nd + 3 < n) { float d = rsqrtf((float)(c3 + 1)); meta[nd + 3] = make_int4(base + e3, c3, __float_as_int(d), 0); dinv[nd + 3] = d; }
  __syncthreads();
  cnt[tid * 4 + 0] = e0; cnt[tid * 4 + 1] = e1;
  cnt[tid * 4 + 2] = e2; cnt[tid * 4 + 3] = e3;
  __syncthreads();

  for (int i = tid; i < m; i += 256) {
    int2 ev = src[i];
    int pos = atomicAdd(&cnt[ev.x & ((1 << BSHIFT) - 1)], 1);
    csr[base + pos] = ev.y;
  }
}

// ---- dense GEMM: Hs[n][F] = bf16(dinv[n] * (X[n][K] @ W[K][F])) ------------

template <int K, int F>
__global__ __launch_bounds__(256) void gemm_kernel(const float* __restrict__ X,
                                                   const float* __restrict__ W,
                                                   const float* __restrict__ dinv,
                                                   __hip_bfloat16* __restrict__ Y, int n) {
  __shared__ float xs[16][K];
  int tid = threadIdx.x;
  int node0 = blockIdx.x * 16;
  constexpr int KV = K / 4;
  const float4* X4 = (const float4*)X;
  for (int i = tid; i < 16 * KV; i += 256) {
    int r = i / KV, c = i % KV;
    int nd = node0 + r;
    float4 v = make_float4(0.f, 0.f, 0.f, 0.f);
    if (nd < n) v = X4[(size_t)nd * KV + c];
    ((float4*)&xs[r][0])[c] = v;
  }
  __syncthreads();
  int g = tid >> 6, lane = tid & 63;
  if (lane < F) {
    float acc0 = 0.f, acc1 = 0.f, acc2 = 0.f, acc3 = 0.f;
#pragma unroll 8
    for (int k = 0; k < K; ++k) {
      float w = W[k * F + lane];
      acc0 += xs[g * 4 + 0][k] * w;
      acc1 += xs[g * 4 + 1][k] * w;
      acc2 += xs[g * 4 + 2][k] * w;
      acc3 += xs[g * 4 + 3][k] * w;
    }
    float accs[4] = {acc0, acc1, acc2, acc3};
#pragma unroll
    for (int j = 0; j < 4; ++j) {
      int nd = node0 + g * 4 + j;
      if (nd < n) Y[(size_t)nd * F + lane] = __float2bfloat16(accs[j] * dinv[nd]);
    }
  }
}

// ---- aggregate: quarter-wave per node, 8 lanes x uint4 per row -------------
// lane = q*16 + sub*8 + fid.  q: node slot (4/wave); sub: edge slot;
// fid: feature octet (8 bf16 = uint4).  One gather instruction = 8 rows
// (4 nodes x 2 edge slots, 1024B).  Combine subs via shfl_xor(8).

__device__ __forceinline__ float bflo(unsigned int u) {
  return __uint_as_float(u << 16);
}
__device__ __forceinline__ float bfhi(unsigned int u) {
  return __uint_as_float(u & 0xffff0000u);
}

template <int F, int MODE>
__global__ __launch_bounds__(256) void agg_kernel(const unsigned short* __restrict__ Hs,
                                                  const int* __restrict__ csr,
                                                  const int4* __restrict__ meta,
                                                  const float* __restrict__ bias,
                                                  float* __restrict__ Y, int n) {
  constexpr int FO = F / 8;                  // feature octets: 8 (F=64), 5 (F=40)
  int wv = (blockIdx.x * 256 + threadIdx.x) >> 6;
  int lane = threadIdx.x & 63;
  int q = lane >> 4;                         // node slot within wave
  int l16 = lane & 15;
  int sub = l16 >> 3;                        // edge slot within node
  int fid = lane & 7;                        // feature-octet id
  int node = wv * 4 + q;
  if (node >= n) return;
  bool activeF = (FO == 8) || (fid < FO);
  int qbase = q * 16;

  int4 mt = meta[node];                      // {off, deg, dinv_bits, 0}
  int s = mt.x, e = mt.x + mt.y;
  float di = __int_as_float(mt.z);

  float a0 = 0.f, a1 = 0.f, a2 = 0.f, a3 = 0.f;
  float a4 = 0.f, a5 = 0.f, a6 = 0.f, a7 = 0.f;
  if (sub == 0 && activeF) {                 // self-loop counted once
    uint4 u = *(const uint4*)(Hs + (size_t)node * F + 8 * fid);
    a0 = bflo(u.x); a1 = bfhi(u.x); a2 = bflo(u.y); a3 = bfhi(u.y);
    a4 = bflo(u.z); a5 = bfhi(u.z); a6 = bflo(u.w); a7 = bfhi(u.w);
  }

  for (int base = s; base < e; base += 16) {
    int rem = e - base;
    int cnt = rem < 16 ? rem : 16;
    int p = csr[base + (l16 < cnt ? l16 : 0)];   // 16 entries per node
    int j = 0;
    for (; j + 8 <= cnt; j += 8) {               // 8 edges/node per iter
      int r0 = __shfl(p, qbase + j + 0 + sub);
      int r1 = __shfl(p, qbase + j + 2 + sub);
      int r2 = __shfl(p, qbase + j + 4 + sub);
      int r3 = __shfl(p, qbase + j + 6 + sub);
      if (activeF) {
        uint4 u0 = *(const uint4*)(Hs + (size_t)r0 * F + 8 * fid);
        uint4 u1 = *(const uint4*)(Hs + (size_t)r1 * F + 8 * fid);
        uint4 u2 = *(const uint4*)(Hs + (size_t)r2 * F + 8 * fid);
        uint4 u3 = *(const uint4*)(Hs + (size_t)r3 * F + 8 * fid);
        a0 += bflo(u0.x); a1 += bfhi(u0.x); a2 += bflo(u0.y); a3 += bfhi(u0.y);
        a4 += bflo(u0.z); a5 += bfhi(u0.z); a6 += bflo(u0.w); a7 += bfhi(u0.w);
        a0 += bflo(u1.x); a1 += bfhi(u1.x); a2 += bflo(u1.y); a3 += bfhi(u1.y);
        a4 += bflo(u1.z); a5 += bfhi(u1.z); a6 += bflo(u1.w); a7 += bfhi(u1.w);
        a0 += bflo(u2.x); a1 += bfhi(u2.x); a2 += bflo(u2.y); a3 += bfhi(u2.y);
        a4 += bflo(u2.z); a5 += bfhi(u2.z); a6 += bflo(u2.w); a7 += bfhi(u2.w);
        a0 += bflo(u3.x); a1 += bfhi(u3.x); a2 += bflo(u3.y); a3 += bfhi(u3.y);
        a4 += bflo(u3.z); a5 += bfhi(u3.z); a6 += bflo(u3.w); a7 += bfhi(u3.w);
      }
    }
    for (; j < cnt; j += 2) {                    // tail (edge pairs via sub)
      int idx = j + sub;
      int r = __shfl(p, qbase + (idx < cnt ? idx : j));
      if (activeF && idx < cnt) {
        uint4 u = *(const uint4*)(Hs + (size_t)r * F + 8 * fid);
        a0 += bflo(u.x); a1 += bfhi(u.x); a2 += bflo(u.y); a3 += bfhi(u.y);
        a4 += bflo(u.z); a5 += bfhi(u.z); a6 += bflo(u.w); a7 += bfhi(u.w);
      }
    }
  }

  // combine the two edge slots (within node)
  a0 += __shfl_xor(a0, 8);
  a1 += __shfl_xor(a1, 8);
  a2 += __shfl_xor(a2, 8);
  a3 += __shfl_xor(a3, 8);
  a4 += __shfl_xor(a4, 8);
  a5 += __shfl_xor(a5, 8);
  a6 += __shfl_xor(a6, 8);
  a7 += __shfl_xor(a7, 8);

  if (MODE == 0) {
    if (sub == 0 && activeF) {
      float4 b0 = *(const float4*)(bias + 8 * fid);
      float4 b1 = *(const float4*)(bias + 8 * fid + 4);
      float v0 = a0 * di + b0.x, v1 = a1 * di + b0.y;
      float v2 = a2 * di + b0.z, v3 = a3 * di + b0.w;
      float v4 = a4 * di + b1.x, v5 = a5 * di + b1.y;
      float v6 = a6 * di + b1.z, v7 = a7 * di + b1.w;
      v0 = v0 > 0.f ? v0 : 0.f; v1 = v1 > 0.f ? v1 : 0.f;
      v2 = v2 > 0.f ? v2 : 0.f; v3 = v3 > 0.f ? v3 : 0.f;
      v4 = v4 > 0.f ? v4 : 0.f; v5 = v5 > 0.f ? v5 : 0.f;
      v6 = v6 > 0.f ? v6 : 0.f; v7 = v7 > 0.f ? v7 : 0.f;
      float* yp = Y + (size_t)node * F + 8 * fid;
      *(float4*)yp = make_float4(v0, v1, v2, v3);
      *(float4*)(yp + 4) = make_float4(v4, v5, v6, v7);
    }
  } else {
    // log-softmax over F; reduction across the 8-lane fid group (xor 4,2,1)
    float v0 = -INFINITY, v1 = -INFINITY, v2 = -INFINITY, v3 = -INFINITY;
    float v4 = -INFINITY, v5 = -INFINITY, v6 = -INFINITY, v7 = -INFINITY;
    if (activeF) {
      float4 b0 = *(const float4*)(bias + 8 * fid);
      float4 b1 = *(const float4*)(bias + 8 * fid + 4);
      v0 = a0 * di + b0.x; v1 = a1 * di + b0.y;
      v2 = a2 * di + b0.z; v3 = a3 * di + b0.w;
      v4 = a4 * di + b1.x; v5 = a5 * di + b1.y;
      v6 = a6 * di + b1.z; v7 = a7 * di + b1.w;
    }
    float m = fmaxf(fmaxf(fmaxf(v0, v1), fmaxf(v2, v3)),
                    fmaxf(fmaxf(v4, v5), fmaxf(v6, v7)));
#pragma unroll
    for (int off = 4; off; off >>= 1) m = fmaxf(m, __shfl_xor(m, off));
    float ex = 0.f;
    if (activeF)
      ex = expf(v0 - m) + expf(v1 - m) + expf(v2 - m) + expf(v3 - m) +
           expf(v4 - m) + expf(v5 - m) + expf(v6 - m) + expf(v7 - m);
#pragma unroll
    for (int off = 4; off; off >>= 1) ex += __shfl_xor(ex, off);
    float lg = m + logf(ex);
    if (sub == 0 && activeF) {
      float* yp = Y + (size_t)node * F + 8 * fid;
      *(float4*)yp = make_float4(v0 - lg, v1 - lg, v2 - lg, v3 - lg);
      *(float4*)(yp + 4) = make_float4(v4 - lg, v5 - lg, v6 - lg, v7 - lg);
    }
  }
}

// ---------------------------------------------------------------------------

extern "C" void kernel_launch(void* const* d_in, const int* in_sizes, int n_in,
                              void* d_out, int out_size, void* d_ws, size_t ws_size,
                              hipStream_t stream) {
  const float* x  = (const float*)d_in[0];
  const int*   ei = (const int*)d_in[1];
  const float* W1 = (const float*)d_in[2];
  const float* b1 = (const float*)d_in[3];
  const float* W2 = (const float*)d_in[4];
  const float* b2 = (const float*)d_in[5];
  const float* W3 = (const float*)d_in[6];
  const float* b3 = (const float*)d_in[7];
  float* out = (float*)d_out;

  const int N = in_sizes[0] / 128;
  const int E = in_sizes[1] / 2;
  const int* erow = ei;       // edge_index[0] = source
  const int* ecol = ei + E;   // edge_index[1] = target

  const int nbuckets = (N + (1 << BSHIFT) - 1) >> BSHIFT;  // 49 (<=64)

  auto align_up = [](size_t v) { return (v + 255) & ~(size_t)255; };
  char* ws = (char*)d_ws;
  size_t off = 0;
  int* bcursor  = (int*)(ws + off); off += align_up(64 * 4);
  int4* meta    = (int4*)(ws + off); off += align_up((size_t)N * 16);
  float* dinv   = (float*)(ws + off); off += align_up((size_t)N * 4);
  int* csr      = (int*)(ws + off); off += align_up((size_t)nbuckets * CAP * 4);
  int2* tmp     = (int2*)(ws + off); off += align_up((size_t)nbuckets * CAP * 8);
  __hip_bfloat16* bufH = (__hip_bfloat16*)(ws + off); off += align_up((size_t)N * 64 * 2);
  float* bufF   = (float*)(ws + off); off += align_up((size_t)N * 64 * 4);
  (void)ws_size;

  const int cb = (E + CHUNK - 1) / CHUNK;

  tinyzero_kernel<<<1, 64, 0, stream>>>(bcursor);
  bucketA_kernel<<<cb, 256, 0, stream>>>(erow, ecol, bcursor, tmp, E);
  scatterB_kernel<<<nbuckets, 256, 0, stream>>>(tmp, bcursor, meta, dinv, csr, N);

  const int gemm_blocks = (N + 15) / 16;
  const int agg_blocks = (N + 15) / 16;  // 4 waves x 4 nodes per 256-thread block

  gemm_kernel<128, 64><<<gemm_blocks, 256, 0, stream>>>(x, W1, dinv, bufH, N);
  agg_kernel<64, 0><<<agg_blocks, 256, 0, stream>>>((const unsigned short*)bufH, csr, meta, b1, bufF, N);

  gemm_kernel<64, 64><<<gemm_blocks, 256, 0, stream>>>(bufF, W2, dinv, bufH, N);
  agg_kernel<64, 0><<<agg_blocks, 256, 0, stream>>>((const unsigned short*)bufH, csr, meta, b2, bufF, N);

  gemm_kernel<64, 40><<<gemm_blocks, 256, 0, stream>>>(bufF, W3, dinv, bufH, N);
  agg_kernel<40, 1><<<agg_blocks, 256, 0, stream>>>((const unsigned short*)bufH, csr, meta, b3, out, N);
}